// Round 18
// baseline (133.687 us; speedup 1.0000x reference)
//
#include <hip/hip_runtime.h>

typedef float v2f __attribute__((ext_vector_type(2)));

#define W 1024
#define H 1024
#define NB 16
#define TX 32
#define TY 42               // output rows per block
#define HR 48               // TY + 6 h-conv rows per block
#define NTH 384             // 6 waves
#define YBLK 25             // ceil(1024/42); last block 16 valid rows (guarded)
#define RSTRIDE (8 * TX)    // dwords per h-row: 8 channels x 32 cols
#define NBLK (32 * YBLK * NB)      // 12800 partials = 50 * 256 exactly
#define NRED1 (NBLK / 256)         // 50 level-1 blocks

// Fused SSIM (r6 structure scaled up: 6-wave blocks, 3 blocks/CU = 18 waves/CU).
//   hbuf layout: [HR][8 channels][TX] floats — the measured conflict-free one.
//   Stage B: 384 tasks = 48 h-rows x 8 col-groups, one per thread (1:1);
//            y-halo redundancy 48/42 = 1.143 (was 1.333). m-loop verbatim
//            from r6 (schedule-sensitive; r14's reorder regressed).
//   Stage C: 12 col-groups: 0-5 4-tall (rows 0-23), 6-11 3-tall (rows 24-41).
template <int TALL>
__device__ __forceinline__ float vconv_ssim(
    const float* __restrict__ hbuf, int base, const float* __restrict__ g,
    int gy0 /* image row of output j=0 */)
{
    v2f sv[4][TALL];
    #pragma unroll
    for (int cp = 0; cp < 4; ++cp)
        #pragma unroll
        for (int j = 0; j < TALL; ++j) sv[cp][j] = (v2f)0.0f;

    #pragma unroll
    for (int dy = 0; dy < TALL + 6; ++dy) {
        v2f p[4];
        #pragma unroll
        for (int cp = 0; cp < 4; ++cp) {
            p[cp].x = hbuf[base + cp * 64];       // channel 2cp
            p[cp].y = hbuf[base + cp * 64 + 32];  // channel 2cp+1
        }
        #pragma unroll
        for (int j = 0; j < TALL; ++j) {
            const int dd = dy - j;
            if (dd >= 0 && dd < 7) {
                const float wg = g[dd];
                #pragma unroll
                for (int cp = 0; cp < 4; ++cp) sv[cp][j] += wg * p[cp];
            }
        }
        base += RSTRIDE;
    }

    float lsum = 0.0f;
    #pragma unroll
    for (int j = 0; j < TALL; ++j) {
        if (gy0 + j < H) {
            const float mu1 = sv[0][j].x, mu2 = sv[0][j].y;
            const float mu3 = sv[1][j].x, E11 = sv[1][j].y;
            const float E22 = sv[2][j].x, E33 = sv[2][j].y;
            const float E12 = sv[3][j].x, E13 = sv[3][j].y;
            const float sig1  = E11 - mu1 * mu1;
            const float sig2  = E22 - mu2 * mu2;
            const float sig3  = E33 - mu3 * mu3;
            const float sig12 = E12 - mu1 * mu2;
            const float sig13 = E13 - mu1 * mu3;
            const float C2 = 9.0e-4f;  // 0.03^2
            const float m12 = (2.0f * sig12 + C2) * __builtin_amdgcn_rcpf(sig1 + sig2 + C2);
            const float m13 = (2.0f * sig13 + C2) * __builtin_amdgcn_rcpf(sig1 + sig3 + C2);
            lsum += (mu2 > mu3) ? m12 : m13;
        }
    }
    return lsum;
}

__global__ __launch_bounds__(NTH, 4) void ssim_main(
    const float* __restrict__ img1, const float* __restrict__ img2,
    const float* __restrict__ img3, const float* __restrict__ win,
    float* __restrict__ partial)
{
    __shared__ __align__(16) float hbuf[HR * RSTRIDE];  // 49152 B -> 3 blocks/CU
    __shared__ float wavesum[6];

    const int tid = threadIdx.x;
    const int x0  = blockIdx.x * TX;
    const int ys0 = blockIdx.y * TY;
    const size_t imoff = (size_t)blockIdx.z * (size_t)(W * H);
    const float* p1 = img1 + imoff;
    const float* p2 = img2 + imoff;
    const float* p3 = img3 + imoff;

    // Separable 1-D gaussian: g[j] = win[3][j] / sqrt(win[3][3])
    float g[7];
    {
        const float inv = 1.0f / sqrtf(win[24]);
        #pragma unroll
        for (int j = 0; j < 7; ++j) g[j] = win[21 + j] * inv;
    }

    // ---- Stage B: horizontal conv, global -> LDS (1 task per thread) ----
    {
        const int br  = tid >> 3;            // 0..47  h-row within block
        const int bc0 = (tid & 7) << 2;      // 0,4,...,28
        const int gy  = ys0 + br - 3;
        const int gx0 = x0 + bc0 - 4;
        const bool xfast = (gx0 >= 0) & (gx0 + 12 <= W);

        v2f accA[8], accB[8];                // j=(0,1) and j=(2,3)
        #pragma unroll
        for (int ch = 0; ch < 8; ++ch) { accA[ch] = (v2f)0.0f; accB[ch] = (v2f)0.0f; }

        if ((gy >= 0) & (gy < H)) {
            const size_t rowoff = (size_t)gy * W;
            float V1[12], V2[12], V3[12];
            if (xfast) {
                const float* q1 = p1 + rowoff + gx0;
                const float* q2 = p2 + rowoff + gx0;
                const float* q3 = p3 + rowoff + gx0;
                *(float4*)&V1[0] = *(const float4*)(q1);
                *(float4*)&V1[4] = *(const float4*)(q1 + 4);
                *(float4*)&V1[8] = *(const float4*)(q1 + 8);
                *(float4*)&V2[0] = *(const float4*)(q2);
                *(float4*)&V2[4] = *(const float4*)(q2 + 4);
                *(float4*)&V2[8] = *(const float4*)(q2 + 8);
                *(float4*)&V3[0] = *(const float4*)(q3);
                *(float4*)&V3[4] = *(const float4*)(q3 + 4);
                *(float4*)&V3[8] = *(const float4*)(q3 + 8);
            } else {
                #pragma unroll
                for (int c = 0; c < 12; ++c) {
                    const int x = gx0 + c;
                    const bool ok = (x >= 0) & (x < W);
                    const size_t off = rowoff + x;
                    V1[c] = ok ? p1[off] : 0.0f;
                    V2[c] = ok ? p2[off] : 0.0f;
                    V3[c] = ok ? p3[off] : 0.0f;
                }
            }

            // weight-pair table: gp[m-1] = {g[m-1], g[m-2]} (edges zero-padded)
            v2f gp[8];
            gp[0] = (v2f){g[0], 0.0f};
            #pragma unroll
            for (int m = 2; m <= 7; ++m) gp[m - 1] = (v2f){g[m - 1], g[m - 2]};
            gp[7] = (v2f){0.0f, g[6]};

            #pragma unroll
            for (int m = 1; m <= 8; ++m) {
                const v2f w = gp[m - 1];
                const float vA1 = V1[m], vA2 = V2[m], vA3 = V3[m];
                const float vB1 = V1[m + 2], vB2 = V2[m + 2], vB3 = V3[m + 2];
                v2f t;
                t = w * vA1;
                accA[0] += t;
                accA[3] += t * vA1;
                accA[6] += t * vA2;
                accA[7] += t * vA3;
                t = w * vA2;
                accA[1] += t;
                accA[4] += t * vA2;
                t = w * vA3;
                accA[2] += t;
                accA[5] += t * vA3;
                t = w * vB1;
                accB[0] += t;
                accB[3] += t * vB1;
                accB[6] += t * vB2;
                accB[7] += t * vB3;
                t = w * vB2;
                accB[1] += t;
                accB[4] += t * vB2;
                t = w * vB3;
                accB[2] += t;
                accB[5] += t * vB3;
            }
        }
        const int wbase = br * RSTRIDE + bc0;
        #pragma unroll
        for (int ch = 0; ch < 8; ++ch) {
            *(v2f*)&hbuf[wbase + ch * TX]     = accA[ch];
            *(v2f*)&hbuf[wbase + ch * TX + 2] = accB[ch];
        }
    }
    __syncthreads();

    // ---- Stage C: vertical conv + SSIM ----
    const int tx  = tid & 31;
    const int grp = tid >> 5;             // 0..11
    float lsum;
    if (grp < 6) {
        const int r0 = grp << 2;          // 0,4,...,20
        lsum = vconv_ssim<4>(hbuf, r0 * RSTRIDE + tx, g, ys0 + r0);
    } else {
        const int r0 = 24 + (grp - 6) * 3;  // 24,27,...,39
        lsum = vconv_ssim<3>(hbuf, r0 * RSTRIDE + tx, g, ys0 + r0);
    }

    // ---- Block reduction (deterministic) ----
    #pragma unroll
    for (int o = 32; o > 0; o >>= 1) lsum += __shfl_down(lsum, o, 64);
    if ((tid & 63) == 0) wavesum[tid >> 6] = lsum;
    __syncthreads();
    if (tid == 0) {
        const float t = ((wavesum[0] + wavesum[1]) + (wavesum[2] + wavesum[3]))
                      + (wavesum[4] + wavesum[5]);
        partial[((size_t)blockIdx.z * gridDim.y + blockIdx.y) * gridDim.x + blockIdx.x] = t;
    }
}

// Level-1 reduction: 50 blocks x 256 threads, each reduces exactly 256
// contiguous partials via deterministic LDS f64 tree.
__global__ __launch_bounds__(256) void ssim_reduce1(
    const float* __restrict__ partial, double* __restrict__ p2)
{
    __shared__ double sh[256];
    const int t = threadIdx.x;
    sh[t] = (double)partial[blockIdx.x * 256 + t];
    __syncthreads();
    #pragma unroll
    for (int o = 128; o > 0; o >>= 1) {
        if (t < o) sh[t] += sh[t + o];
        __syncthreads();
    }
    if (t == 0) p2[blockIdx.x] = sh[0];
}

// Level-2: one block sums the 50 doubles (fixed order) and writes the mean.
__global__ __launch_bounds__(64) void ssim_reduce2(
    const double* __restrict__ p2, float* __restrict__ out)
{
    __shared__ double sh[64];
    const int t = threadIdx.x;
    sh[t] = (t < NRED1) ? p2[t] : 0.0;
    __syncthreads();
    #pragma unroll
    for (int o = 32; o > 0; o >>= 1) {
        if (t < o) sh[t] += sh[t + o];
        __syncthreads();
    }
    if (t == 0) out[0] = (float)(sh[0] / (double)((size_t)NB * W * H));
}

extern "C" void kernel_launch(void* const* d_in, const int* in_sizes, int n_in,
                              void* d_out, int out_size, void* d_ws, size_t ws_size,
                              hipStream_t stream) {
    const float* img1 = (const float*)d_in[0];
    const float* img2 = (const float*)d_in[1];
    const float* img3 = (const float*)d_in[2];
    const float* win  = (const float*)d_in[3];
    float* out = (float*)d_out;
    float* partial = (float*)d_ws;                                   // NBLK floats
    double* p2 = (double*)((char*)d_ws + (size_t)NBLK * 4);          // 8B-aligned

    dim3 grid(W / TX, YBLK, NB);  // 32 x 25 x 16 = 12800 blocks
    ssim_main<<<grid, NTH, 0, stream>>>(img1, img2, img3, win, partial);
    ssim_reduce1<<<NRED1, 256, 0, stream>>>(partial, p2);
    ssim_reduce2<<<1, 64, 0, stream>>>(p2, out);
}

// Round 19
// 103.423 us; speedup vs baseline: 1.2926x; 1.2926x over previous
//
#include <hip/hip_runtime.h>

typedef float v2f __attribute__((ext_vector_type(2)));

#define W 1024
#define H 1024
#define NB 16
#define TX 32
#define TY 18
#define HR 24               // TY + 6 h-conv rows per block
#define NTH 192             // 3 waves
#define YBLK ((H + TY - 1) / TY)   // 57 (last block 2 rows OOB, guarded)
#define RSTRIDE (8 * TX)    // dwords per h-row: 8 channels x 32 cols
#define NBLK (32 * YBLK * NB)      // 29184 partials = 114 * 256 exactly
#define NRED1 (NBLK / 256)         // 114 level-1 blocks

// Fused SSIM — FINAL configuration (best measured: bench 103.5 µs).
//   hbuf layout: [HR][8 channels][TX] floats — the only measured conflict-free
//   layout (pair/quad interleaves hit 5.2e6-1.68e7 conflict cycles).
//   Stage B: 192 tasks = 24 rows x 8 col-groups, one per thread; weight-pair
//            m-loop verbatim (schedule-sensitive: reorders regress ~13%).
//   Stage C: 32 cols x 6 rowgroups x 3-tall vertical conv + SSIM map.
//   3-wave blocks / 24.6 KB LDS / 4-5 blocks/CU is the measured optimum
//   (scaling up or down regresses; occupancy forcing spills or no-ops).
__global__ __launch_bounds__(NTH, 4) void ssim_main(
    const float* __restrict__ img1, const float* __restrict__ img2,
    const float* __restrict__ img3, const float* __restrict__ win,
    float* __restrict__ partial)
{
    __shared__ __align__(16) float hbuf[HR * RSTRIDE];  // 24576 B
    __shared__ float wavesum[3];

    const int tid = threadIdx.x;
    const int x0  = blockIdx.x * TX;
    const int ys0 = blockIdx.y * TY;
    const size_t imoff = (size_t)blockIdx.z * (size_t)(W * H);
    const float* p1 = img1 + imoff;
    const float* p2 = img2 + imoff;
    const float* p3 = img3 + imoff;

    // Separable 1-D gaussian: g[j] = win[3][j] / sqrt(win[3][3])
    float g[7];
    {
        const float inv = 1.0f / sqrtf(win[24]);
        #pragma unroll
        for (int j = 0; j < 7; ++j) g[j] = win[21 + j] * inv;
    }

    // ---- Stage B: horizontal conv, global -> LDS (1 task per thread) ----
    {
        const int br  = tid >> 3;            // 0..23  h-row within block
        const int bc0 = (tid & 7) << 2;      // 0,4,...,28
        const int gy  = ys0 + br - 3;
        const int gx0 = x0 + bc0 - 4;
        const bool xfast = (gx0 >= 0) & (gx0 + 12 <= W);

        v2f accA[8], accB[8];                // j=(0,1) and j=(2,3)
        #pragma unroll
        for (int ch = 0; ch < 8; ++ch) { accA[ch] = (v2f)0.0f; accB[ch] = (v2f)0.0f; }

        if ((gy >= 0) & (gy < H)) {
            const size_t rowoff = (size_t)gy * W;
            float V1[12], V2[12], V3[12];
            if (xfast) {
                const float* q1 = p1 + rowoff + gx0;
                const float* q2 = p2 + rowoff + gx0;
                const float* q3 = p3 + rowoff + gx0;
                *(float4*)&V1[0] = *(const float4*)(q1);
                *(float4*)&V1[4] = *(const float4*)(q1 + 4);
                *(float4*)&V1[8] = *(const float4*)(q1 + 8);
                *(float4*)&V2[0] = *(const float4*)(q2);
                *(float4*)&V2[4] = *(const float4*)(q2 + 4);
                *(float4*)&V2[8] = *(const float4*)(q2 + 8);
                *(float4*)&V3[0] = *(const float4*)(q3);
                *(float4*)&V3[4] = *(const float4*)(q3 + 4);
                *(float4*)&V3[8] = *(const float4*)(q3 + 8);
            } else {
                #pragma unroll
                for (int c = 0; c < 12; ++c) {
                    const int x = gx0 + c;
                    const bool ok = (x >= 0) & (x < W);
                    const size_t off = rowoff + x;
                    V1[c] = ok ? p1[off] : 0.0f;
                    V2[c] = ok ? p2[off] : 0.0f;
                    V3[c] = ok ? p3[off] : 0.0f;
                }
            }

            // weight-pair table: gp[m-1] = {g[m-1], g[m-2]} (edges zero-padded)
            v2f gp[8];
            gp[0] = (v2f){g[0], 0.0f};
            #pragma unroll
            for (int m = 2; m <= 7; ++m) gp[m - 1] = (v2f){g[m - 1], g[m - 2]};
            gp[7] = (v2f){0.0f, g[6]};

            #pragma unroll
            for (int m = 1; m <= 8; ++m) {
                const v2f w = gp[m - 1];
                const float vA1 = V1[m], vA2 = V2[m], vA3 = V3[m];
                const float vB1 = V1[m + 2], vB2 = V2[m + 2], vB3 = V3[m + 2];
                v2f t;
                t = w * vA1;
                accA[0] += t;
                accA[3] += t * vA1;
                accA[6] += t * vA2;
                accA[7] += t * vA3;
                t = w * vA2;
                accA[1] += t;
                accA[4] += t * vA2;
                t = w * vA3;
                accA[2] += t;
                accA[5] += t * vA3;
                t = w * vB1;
                accB[0] += t;
                accB[3] += t * vB1;
                accB[6] += t * vB2;
                accB[7] += t * vB3;
                t = w * vB2;
                accB[1] += t;
                accB[4] += t * vB2;
                t = w * vB3;
                accB[2] += t;
                accB[5] += t * vB3;
            }
        }
        const int wbase = br * RSTRIDE + bc0;
        #pragma unroll
        for (int ch = 0; ch < 8; ++ch) {
            *(v2f*)&hbuf[wbase + ch * TX]     = accA[ch];
            *(v2f*)&hbuf[wbase + ch * TX + 2] = accB[ch];
        }
    }
    __syncthreads();

    // ---- Stage C: vertical conv (3-tall), packed across channel pairs ----
    const int tx = tid & 31;
    const int r0 = (tid >> 5) * 3;        // 0,3,...,15

    v2f sv[4][3];
    #pragma unroll
    for (int cp = 0; cp < 4; ++cp)
        #pragma unroll
        for (int j = 0; j < 3; ++j) sv[cp][j] = (v2f)0.0f;

    int base = r0 * RSTRIDE + tx;
    #pragma unroll
    for (int dy = 0; dy < 9; ++dy) {
        v2f p[4];
        #pragma unroll
        for (int cp = 0; cp < 4; ++cp) {
            p[cp].x = hbuf[base + cp * 64];       // channel 2cp
            p[cp].y = hbuf[base + cp * 64 + 32];  // channel 2cp+1
        }
        #pragma unroll
        for (int j = 0; j < 3; ++j) {
            const int dd = dy - j;
            if (dd >= 0 && dd < 7) {
                const float wg = g[dd];
                #pragma unroll
                for (int cp = 0; cp < 4; ++cp) sv[cp][j] += wg * p[cp];
            }
        }
        base += RSTRIDE;
    }

    float lsum = 0.0f;
    #pragma unroll
    for (int j = 0; j < 3; ++j) {
        if (ys0 + r0 + j < H) {
            const float mu1 = sv[0][j].x, mu2 = sv[0][j].y;
            const float mu3 = sv[1][j].x, E11 = sv[1][j].y;
            const float E22 = sv[2][j].x, E33 = sv[2][j].y;
            const float E12 = sv[3][j].x, E13 = sv[3][j].y;
            const float sig1  = E11 - mu1 * mu1;
            const float sig2  = E22 - mu2 * mu2;
            const float sig3  = E33 - mu3 * mu3;
            const float sig12 = E12 - mu1 * mu2;
            const float sig13 = E13 - mu1 * mu3;
            const float C2 = 9.0e-4f;  // 0.03^2
            const float m12 = (2.0f * sig12 + C2) * __builtin_amdgcn_rcpf(sig1 + sig2 + C2);
            const float m13 = (2.0f * sig13 + C2) * __builtin_amdgcn_rcpf(sig1 + sig3 + C2);
            lsum += (mu2 > mu3) ? m12 : m13;
        }
    }

    // ---- Block reduction (deterministic) ----
    #pragma unroll
    for (int o = 32; o > 0; o >>= 1) lsum += __shfl_down(lsum, o, 64);
    if ((tid & 63) == 0) wavesum[tid >> 6] = lsum;
    __syncthreads();
    if (tid == 0) {
        partial[((size_t)blockIdx.z * gridDim.y + blockIdx.y) * gridDim.x + blockIdx.x] =
            wavesum[0] + wavesum[1] + wavesum[2];
    }
}

// Level-1 reduction: 114 blocks x 256 threads, each reduces exactly 256
// contiguous partials via deterministic LDS f64 tree.
__global__ __launch_bounds__(256) void ssim_reduce1(
    const float* __restrict__ partial, double* __restrict__ p2)
{
    __shared__ double sh[256];
    const int t = threadIdx.x;
    sh[t] = (double)partial[blockIdx.x * 256 + t];
    __syncthreads();
    #pragma unroll
    for (int o = 128; o > 0; o >>= 1) {
        if (t < o) sh[t] += sh[t + o];
        __syncthreads();
    }
    if (t == 0) p2[blockIdx.x] = sh[0];
}

// Level-2: one block sums the 114 doubles (fixed order) and writes the mean.
__global__ __launch_bounds__(128) void ssim_reduce2(
    const double* __restrict__ p2, float* __restrict__ out)
{
    __shared__ double sh[128];
    const int t = threadIdx.x;
    sh[t] = (t < NRED1) ? p2[t] : 0.0;
    __syncthreads();
    #pragma unroll
    for (int o = 64; o > 0; o >>= 1) {
        if (t < o) sh[t] += sh[t + o];
        __syncthreads();
    }
    if (t == 0) out[0] = (float)(sh[0] / (double)((size_t)NB * W * H));
}

extern "C" void kernel_launch(void* const* d_in, const int* in_sizes, int n_in,
                              void* d_out, int out_size, void* d_ws, size_t ws_size,
                              hipStream_t stream) {
    const float* img1 = (const float*)d_in[0];
    const float* img2 = (const float*)d_in[1];
    const float* img3 = (const float*)d_in[2];
    const float* win  = (const float*)d_in[3];
    float* out = (float*)d_out;
    float* partial = (float*)d_ws;                                   // NBLK floats
    double* p2 = (double*)((char*)d_ws + (size_t)NBLK * 4);          // 8B-aligned

    dim3 grid(W / TX, YBLK, NB);  // 32 x 57 x 16 = 29184 blocks
    ssim_main<<<grid, NTH, 0, stream>>>(img1, img2, img3, win, partial);
    ssim_reduce1<<<NRED1, 256, 0, stream>>>(partial, p2);
    ssim_reduce2<<<1, 128, 0, stream>>>(p2, out);
}